// Round 15
// baseline (235.959 us; speedup 1.0000x reference)
//
#include <hip/hip_runtime.h>

// DarcyLoss: B=4096, C=2, H=W=64. Inputs (f32): model_out, target, x0_hat [B,2,64,64], var [B].
// loss = mean((mo-tg)^2) + mean_b( min(0.5*r_b^2/var_b, 27.6310211159) )
// r_b = (sum(eq0)+sum(bc)) / (64*64*3);  source f_s sums to 0 -> omitted.
//
// R15 = R11 (best: 70.9us, 9.2 B/cyc/CU = 90% of the m13 per-CU vmem ceiling)
// with the final reduction FUSED via last-block-done: per-wave partials ->
// device fence -> atomic ticket -> the last block re-reads all partials in
// fixed order (double accum, bitwise deterministic) and writes out[0].
// Counter zeroed each launch by hipMemsetAsync (graph-capturable).
// Main structure: wave = batch, float2 row-pair stencil (rows {2t,2t+1},
// lanes 0..31 even row / 32..63 odd row, 2 cols/lane), 8-slot pipeline,
// __shfl_xor(32) verticals with carried swizzles, lane+-1 horizontals,
// fused nontemporal mo/tg streaming. No LDS staging, no spill (VGPR ~40).

#define NB 4096
#define HW 4096          // 64*64
#define CHW 8192         // 2*64*64

typedef float vf4 __attribute__((ext_vector_type(4)));
typedef float vf2 __attribute__((ext_vector_type(2)));

__device__ __forceinline__ vf2 swz32(vf2 v) {          // lane ^ 32
    vf2 r; r.x = __shfl_xor(v.x, 32); r.y = __shfl_xor(v.y, 32); return r;
}
__device__ __forceinline__ vf2 shl1(vf2 v, int lane) { // from lane-1
    vf2 r; const int s = (lane + 63) & 63;
    r.x = __shfl(v.x, s); r.y = __shfl(v.y, s); return r;
}
__device__ __forceinline__ vf2 shr1(vf2 v, int lane) { // from lane+1
    vf2 r; const int s = (lane + 1) & 63;
    r.x = __shfl(v.x, s); r.y = __shfl(v.y, s); return r;
}
__device__ __forceinline__ vf2 sel2(bool c, vf2 a, vf2 b) {
    vf2 r; r.x = c ? a.x : b.x; r.y = c ? a.y : b.y; return r;
}

__global__ __launch_bounds__(256, 4) void darcy_wave_kernel(
    const float* __restrict__ mo, const float* __restrict__ tg,
    const float* __restrict__ x0, const float* __restrict__ var,
    float* __restrict__ ws_res, float* __restrict__ ws_d,
    unsigned int* __restrict__ ctr, float* __restrict__ out)
{
    constexpr float INV2D = 31.5f;            // 1/(2D), D=1/63
    constexpr float INVD2 = 3969.0f;          // 1/D^2
    constexpr float CLAMP = 27.6310211159f;

    const int wv   = threadIdx.x >> 6;
    const int lane = threadIdx.x & 63;
    const int b    = blockIdx.x * 4 + wv;
    const bool h   = (lane >> 5) != 0;        // false: even row, true: odd row
    const bool jlo = ((lane & 31) == 0);      // cell a is col 0
    const bool jhi = ((lane & 31) == 31);     // cell b is col 63

    const vf2* p2 = (const vf2*)(x0 + (size_t)b * CHW);   // 2048 vf2 (p plane)
    const vf2* q2 = p2 + 2048;                            // perm plane
    const vf4* m4 = (const vf4*)(mo + (size_t)b * CHW);   // 2048 f4
    const vf4* g4 = (const vf4*)(tg + (size_t)b * CHW);

    float rsum = 0.0f, dsum = 0.0f;

    // ---- 8-slot vf2 row-pair pipeline; preload blocks 0..5 ----
    vf2 pw[8], qw[8];
    #pragma unroll
    for (int k = 0; k < 6; ++k) {
        pw[k] = p2[(k << 6) + lane];
        qw[k] = q2[(k << 6) + lane];
    }

    // swizzle carries: s_cur/s_prv per plane (s_prv masked at t=0)
    vf2 spc = swz32(pw[0]), sqc = swz32(qw[0]);
    vf2 spp = spc,          sqp = sqc;

    #pragma unroll
    for (int t = 0; t < 32; ++t) {
        // prefetch block t+6 (rows 2t+12, 2t+13)
        if (t + 6 < 32) {
            pw[(t + 6) & 7] = p2[((t + 6) << 6) + lane];
            qw[(t + 6) & 7] = q2[((t + 6) << 6) + lane];
        }
        // fused data-loss chunk t (nontemporal: zero reuse)
        {
            vf4 a = __builtin_nontemporal_load(m4 + (t << 6) + lane);
            vf4 g = __builtin_nontemporal_load(g4 + (t << 6) + lane);
            vf4 e = a - g;
            dsum += e.x * e.x + e.y * e.y + e.z * e.z + e.w * e.w;
        }

        const vf2 pc  = pw[t & 7],       qc  = qw[t & 7];
        const vf2 pnx = pw[(t + 1) & 7], qnx = qw[(t + 1) & 7];  // garbage at t=31 (masked)
        const vf2 spn = swz32(pnx), sqn = swz32(qnx);

        // vertical neighbors (rows r+-1): even row -> {s_cur, s_prv}, odd -> {s_new, s_cur}
        const vf2 upP = sel2(h, spn, spc), dnP = sel2(h, spc, spp);
        const vf2 upQ = sel2(h, sqn, sqc), dnQ = sel2(h, sqc, sqp);

        vf2 pd0  = (upP - dnP) * INV2D;
        vf2 pd00 = (upP - 2.0f * pc + dnP) * INVD2;
        vf2 qd0  = (upQ - dnQ) * INV2D;

        if (t == 0) {      // row 0 one-sided (even-row lanes): f1=spc, f2=pnx, f3=spn
            vf2 od0  = (-3.0f * pc + 4.0f * spc - pnx) * INV2D;
            vf2 od00 = (2.0f * pc - 5.0f * spc + 4.0f * pnx - spn) * INVD2;
            vf2 oq0  = (-3.0f * qc + 4.0f * sqc - qnx) * INV2D;
            pd0 = sel2(!h, od0, pd0); pd00 = sel2(!h, od00, pd00); qd0 = sel2(!h, oq0, qd0);
        }
        if (t == 31) {     // row 63 one-sided (odd-row lanes): f62=spc, f61=prv, f60=spp
            const vf2 pprv = pw[(t - 1) & 7], qprv = qw[(t - 1) & 7];
            vf2 od0  = (3.0f * pc - 4.0f * spc + pprv) * INV2D;
            vf2 od00 = (2.0f * pc - 5.0f * spc + 4.0f * pprv - spp) * INVD2;
            vf2 oq0  = (3.0f * qc - 4.0f * sqc + qprv) * INV2D;
            pd0 = sel2(h, od0, pd0); pd00 = sel2(h, od00, pd00); qd0 = sel2(h, oq0, qd0);
        }

        // horizontal neighbors
        const vf2 l2p = shl1(pc, lane), r2p = shr1(pc, lane);
        const vf2 l2q = shl1(qc, lane), r2q = shr1(qc, lane);

        // cell a (col c0): interior left=l2p.y, right=pc.y; j=0 one-sided
        float pd1a  = (pc.y - l2p.y) * INV2D;
        float pd11a = (pc.y - 2.0f * pc.x + l2p.y) * INVD2;
        float qd1a  = (qc.y - l2q.y) * INV2D;
        if (jlo) {
            pd1a  = (-3.0f * pc.x + 4.0f * pc.y - r2p.x) * INV2D;
            pd11a = (2.0f * pc.x - 5.0f * pc.y + 4.0f * r2p.x - r2p.y) * INVD2;
            qd1a  = (-3.0f * qc.x + 4.0f * qc.y - r2q.x) * INV2D;
        }
        // cell b (col c0+1): interior left=pc.x, right=r2p.x; j=63 one-sided
        float pd1b  = (r2p.x - pc.x) * INV2D;
        float pd11b = (r2p.x - 2.0f * pc.y + pc.x) * INVD2;
        float qd1b  = (r2q.x - qc.x) * INV2D;
        if (jhi) {
            pd1b  = (3.0f * pc.y - 4.0f * pc.x + l2p.y) * INV2D;
            pd11b = (2.0f * pc.y - 5.0f * pc.x + 4.0f * l2p.y - l2p.x) * INVD2;
            qd1b  = (3.0f * qc.y - 4.0f * qc.x + l2q.y) * INV2D;
        }

        // eq0 = -(perm*(pd00+pd11) + qd0*pd0 + qd1*pd1), two cells
        rsum -= qc.x * (pd00.x + pd11a) + qd0.x * pd0.x + qd1a * pd1a;
        rsum -= qc.y * (pd00.y + pd11b) + qd0.y * pd0.y + qd1b * pd1b;

        // boundary-condition terms
        if (t == 0)  rsum -= (!h) ? (pd0.x + pd0.y) : 0.0f;   // i=0
        if (t == 31) rsum += h    ? (pd0.x + pd0.y) : 0.0f;   // i=63
        rsum += jlo ? pd1a : 0.0f;                            // j=0
        rsum -= jhi ? pd1b : 0.0f;                            // j=63

        // rotate swizzle carries
        spp = spc; spc = spn; sqp = sqc; sqc = sqn;
    }

    // ---- per-wave reduction (wave == batch); write partials ----
    #pragma unroll
    for (int off = 32; off > 0; off >>= 1) {
        rsum += __shfl_down(rsum, off);
        dsum += __shfl_down(dsum, off);
    }
    if (lane == 0) {
        const float r = rsum * (1.0f / (64.0f * 64.0f * 3.0f));
        float res = 0.5f * r * r / var[b];
        ws_res[b] = fminf(res, CLAMP);
        ws_d[b]   = dsum;
    }

    // ---- fused finale: last block reduces all partials (deterministic) ----
    __threadfence();                          // release this block's partials
    __syncthreads();
    __shared__ bool amlast;
    __shared__ double red[8];
    if (threadIdx.x == 0)
        amlast = (atomicAdd(ctr, 1u) == gridDim.x - 1);
    __syncthreads();
    if (!amlast) return;

    __threadfence();                          // acquire all blocks' partials
    const int t = threadIdx.x;
    double rs = 0.0, ds = 0.0;
    for (int i = t; i < NB; i += 256) {       // fixed order -> deterministic
        rs += (double)ws_res[i];
        ds += (double)ws_d[i];
    }
    #pragma unroll
    for (int off = 32; off > 0; off >>= 1) {
        rs += __shfl_down(rs, off);
        ds += __shfl_down(ds, off);
    }
    const int wid = t >> 6, ln = t & 63;
    if (ln == 0) { red[wid] = rs; red[4 + wid] = ds; }
    __syncthreads();
    if (t == 0) {
        const double R  = red[0] + red[1] + red[2] + red[3];
        const double Dd = red[4] + red[5] + red[6] + red[7];
        out[0] = (float)(Dd / ((double)NB * (double)CHW) + R / (double)NB);
    }
}

extern "C" void kernel_launch(void* const* d_in, const int* in_sizes, int n_in,
                              void* d_out, int out_size, void* d_ws, size_t ws_size,
                              hipStream_t stream) {
    const float* mo  = (const float*)d_in[0];
    const float* tg  = (const float*)d_in[1];
    const float* x0  = (const float*)d_in[2];
    const float* var = (const float*)d_in[3];
    float* out = (float*)d_out;

    float* ws_res = (float*)d_ws;                      // NB floats
    float* ws_d   = ws_res + NB;                       // NB floats
    unsigned int* ctr = (unsigned int*)(ws_d + NB);    // 1 uint ticket

    hipMemsetAsync(ctr, 0, sizeof(unsigned int), stream);   // graph-capturable
    darcy_wave_kernel<<<NB / 4, 256, 0, stream>>>(mo, tg, x0, var,
                                                  ws_res, ws_d, ctr, out);
}

// Round 16
// 70.442 us; speedup vs baseline: 3.3497x; 3.3497x over previous
//
#include <hip/hip_runtime.h>

// DarcyLoss: B=4096, C=2, H=W=64. Inputs (f32): model_out, target, x0_hat [B,2,64,64], var [B].
// loss = mean((mo-tg)^2) + mean_b( min(0.5*r_b^2/var_b, 27.6310211159) )
// r_b = (sum(eq0)+sum(bc)) / (64*64*3);  source f_s sums to 0 -> omitted.
//
// R16 = R11 verbatim (best measured: 70.9 us = 9.2 B/cyc/CU, ~90% of the m13
// per-CU vmem ceiling). R15's fused-finale regression showed device-scope
// fences (L2 wb/inv on non-coherent XCD L2s) cost ~165 us; the separate
// 4-us final kernel is the right trade.
// Structure: wave = batch, float2 row-pair stencil. Block-iter t loads rows
// {2t,2t+1} of p and q as ONE vf2 load each (512 B/wave): lanes 0..31 even row,
// lanes 32..63 odd row, 2 cols/lane. 8-slot window, prefetch dist 6.
// Verticals via __shfl_xor(32) with carried swizzles (sxn(t)=sxc(t+1));
// horizontals via lane+-1; rows/cols 0/63 one-sided from {prv,cur,nxt}.
// mo/tg fused nontemporal f4 streaming. No LDS, no barriers, no atomics.

#define NB 4096
#define HW 4096          // 64*64
#define CHW 8192         // 2*64*64

typedef float vf4 __attribute__((ext_vector_type(4)));
typedef float vf2 __attribute__((ext_vector_type(2)));

__device__ __forceinline__ vf2 swz32(vf2 v) {          // lane ^ 32
    vf2 r; r.x = __shfl_xor(v.x, 32); r.y = __shfl_xor(v.y, 32); return r;
}
__device__ __forceinline__ vf2 shl1(vf2 v, int lane) { // from lane-1
    vf2 r; const int s = (lane + 63) & 63;
    r.x = __shfl(v.x, s); r.y = __shfl(v.y, s); return r;
}
__device__ __forceinline__ vf2 shr1(vf2 v, int lane) { // from lane+1
    vf2 r; const int s = (lane + 1) & 63;
    r.x = __shfl(v.x, s); r.y = __shfl(v.y, s); return r;
}
__device__ __forceinline__ vf2 sel2(bool c, vf2 a, vf2 b) {
    vf2 r; r.x = c ? a.x : b.x; r.y = c ? a.y : b.y; return r;
}

__global__ __launch_bounds__(256, 4) void darcy_wave_kernel(
    const float* __restrict__ mo, const float* __restrict__ tg,
    const float* __restrict__ x0, const float* __restrict__ var,
    float* __restrict__ ws_res, float* __restrict__ ws_d)
{
    constexpr float INV2D = 31.5f;            // 1/(2D), D=1/63
    constexpr float INVD2 = 3969.0f;          // 1/D^2
    constexpr float CLAMP = 27.6310211159f;

    const int wv   = threadIdx.x >> 6;
    const int lane = threadIdx.x & 63;
    const int b    = blockIdx.x * 4 + wv;
    const bool h   = (lane >> 5) != 0;        // false: even row, true: odd row
    const bool jlo = ((lane & 31) == 0);      // cell a is col 0
    const bool jhi = ((lane & 31) == 31);     // cell b is col 63

    const vf2* p2 = (const vf2*)(x0 + (size_t)b * CHW);   // 2048 vf2 (p plane)
    const vf2* q2 = p2 + 2048;                            // perm plane
    const vf4* m4 = (const vf4*)(mo + (size_t)b * CHW);   // 2048 f4
    const vf4* g4 = (const vf4*)(tg + (size_t)b * CHW);

    float rsum = 0.0f, dsum = 0.0f;

    // ---- 8-slot vf2 row-pair pipeline; preload blocks 0..5 ----
    vf2 pw[8], qw[8];
    #pragma unroll
    for (int k = 0; k < 6; ++k) {
        pw[k] = p2[(k << 6) + lane];
        qw[k] = q2[(k << 6) + lane];
    }

    // swizzle carries: s_cur/s_prv per plane (s_prv masked at t=0)
    vf2 spc = swz32(pw[0]), sqc = swz32(qw[0]);
    vf2 spp = spc,          sqp = sqc;

    #pragma unroll
    for (int t = 0; t < 32; ++t) {
        // prefetch block t+6 (rows 2t+12, 2t+13)
        if (t + 6 < 32) {
            pw[(t + 6) & 7] = p2[((t + 6) << 6) + lane];
            qw[(t + 6) & 7] = q2[((t + 6) << 6) + lane];
        }
        // fused data-loss chunk t (nontemporal: zero reuse)
        {
            vf4 a = __builtin_nontemporal_load(m4 + (t << 6) + lane);
            vf4 g = __builtin_nontemporal_load(g4 + (t << 6) + lane);
            vf4 e = a - g;
            dsum += e.x * e.x + e.y * e.y + e.z * e.z + e.w * e.w;
        }

        const vf2 pc  = pw[t & 7],       qc  = qw[t & 7];
        const vf2 pnx = pw[(t + 1) & 7], qnx = qw[(t + 1) & 7];  // garbage at t=31 (masked)
        const vf2 spn = swz32(pnx), sqn = swz32(qnx);

        // vertical neighbors (rows r+-1): even row -> {s_cur, s_prv}, odd -> {s_new, s_cur}
        const vf2 upP = sel2(h, spn, spc), dnP = sel2(h, spc, spp);
        const vf2 upQ = sel2(h, sqn, sqc), dnQ = sel2(h, sqc, sqp);

        vf2 pd0  = (upP - dnP) * INV2D;
        vf2 pd00 = (upP - 2.0f * pc + dnP) * INVD2;
        vf2 qd0  = (upQ - dnQ) * INV2D;

        if (t == 0) {      // row 0 one-sided (even-row lanes): f1=spc, f2=pnx, f3=spn
            vf2 od0  = (-3.0f * pc + 4.0f * spc - pnx) * INV2D;
            vf2 od00 = (2.0f * pc - 5.0f * spc + 4.0f * pnx - spn) * INVD2;
            vf2 oq0  = (-3.0f * qc + 4.0f * sqc - qnx) * INV2D;
            pd0 = sel2(!h, od0, pd0); pd00 = sel2(!h, od00, pd00); qd0 = sel2(!h, oq0, qd0);
        }
        if (t == 31) {     // row 63 one-sided (odd-row lanes): f62=spc, f61=prv, f60=spp
            const vf2 pprv = pw[(t - 1) & 7], qprv = qw[(t - 1) & 7];
            vf2 od0  = (3.0f * pc - 4.0f * spc + pprv) * INV2D;
            vf2 od00 = (2.0f * pc - 5.0f * spc + 4.0f * pprv - spp) * INVD2;
            vf2 oq0  = (3.0f * qc - 4.0f * sqc + qprv) * INV2D;
            pd0 = sel2(h, od0, pd0); pd00 = sel2(h, od00, pd00); qd0 = sel2(h, oq0, qd0);
        }

        // horizontal neighbors
        const vf2 l2p = shl1(pc, lane), r2p = shr1(pc, lane);
        const vf2 l2q = shl1(qc, lane), r2q = shr1(qc, lane);

        // cell a (col c0): interior left=l2p.y, right=pc.y; j=0 one-sided
        float pd1a  = (pc.y - l2p.y) * INV2D;
        float pd11a = (pc.y - 2.0f * pc.x + l2p.y) * INVD2;
        float qd1a  = (qc.y - l2q.y) * INV2D;
        if (jlo) {
            pd1a  = (-3.0f * pc.x + 4.0f * pc.y - r2p.x) * INV2D;
            pd11a = (2.0f * pc.x - 5.0f * pc.y + 4.0f * r2p.x - r2p.y) * INVD2;
            qd1a  = (-3.0f * qc.x + 4.0f * qc.y - r2q.x) * INV2D;
        }
        // cell b (col c0+1): interior left=pc.x, right=r2p.x; j=63 one-sided
        float pd1b  = (r2p.x - pc.x) * INV2D;
        float pd11b = (r2p.x - 2.0f * pc.y + pc.x) * INVD2;
        float qd1b  = (r2q.x - qc.x) * INV2D;
        if (jhi) {
            pd1b  = (3.0f * pc.y - 4.0f * pc.x + l2p.y) * INV2D;
            pd11b = (2.0f * pc.y - 5.0f * pc.x + 4.0f * l2p.y - l2p.x) * INVD2;
            qd1b  = (3.0f * qc.y - 4.0f * qc.x + l2q.y) * INV2D;
        }

        // eq0 = -(perm*(pd00+pd11) + qd0*pd0 + qd1*pd1), two cells
        rsum -= qc.x * (pd00.x + pd11a) + qd0.x * pd0.x + qd1a * pd1a;
        rsum -= qc.y * (pd00.y + pd11b) + qd0.y * pd0.y + qd1b * pd1b;

        // boundary-condition terms
        if (t == 0)  rsum -= (!h) ? (pd0.x + pd0.y) : 0.0f;   // i=0
        if (t == 31) rsum += h    ? (pd0.x + pd0.y) : 0.0f;   // i=63
        rsum += jlo ? pd1a : 0.0f;                            // j=0
        rsum -= jhi ? pd1b : 0.0f;                            // j=63

        // rotate swizzle carries
        spp = spc; spc = spn; sqp = sqc; sqc = sqn;
    }

    // ---- per-wave reduction (wave == batch) ----
    #pragma unroll
    for (int off = 32; off > 0; off >>= 1) {
        rsum += __shfl_down(rsum, off);
        dsum += __shfl_down(dsum, off);
    }
    if (lane == 0) {
        const float r = rsum * (1.0f / (64.0f * 64.0f * 3.0f));
        float res = 0.5f * r * r / var[b];
        ws_res[b] = fminf(res, CLAMP);
        ws_d[b]   = dsum;
    }
}

__global__ __launch_bounds__(256) void darcy_final_kernel(
    const float* __restrict__ ws_res, const float* __restrict__ ws_d,
    float* __restrict__ out)
{
    const int t = threadIdx.x;
    double rs = 0.0, ds = 0.0;
    for (int i = t; i < NB; i += 256) {
        rs += (double)ws_res[i];
        ds += (double)ws_d[i];
    }
    #pragma unroll
    for (int off = 32; off > 0; off >>= 1) {
        rs += __shfl_down(rs, off);
        ds += __shfl_down(ds, off);
    }
    __shared__ double red[8];
    const int wid = t >> 6, lane = t & 63;
    if (lane == 0) { red[wid] = rs; red[4 + wid] = ds; }
    __syncthreads();
    if (t == 0) {
        const double R  = red[0] + red[1] + red[2] + red[3];
        const double Dd = red[4] + red[5] + red[6] + red[7];
        out[0] = (float)(Dd / ((double)NB * (double)CHW) + R / (double)NB);
    }
}

extern "C" void kernel_launch(void* const* d_in, const int* in_sizes, int n_in,
                              void* d_out, int out_size, void* d_ws, size_t ws_size,
                              hipStream_t stream) {
    const float* mo  = (const float*)d_in[0];
    const float* tg  = (const float*)d_in[1];
    const float* x0  = (const float*)d_in[2];
    const float* var = (const float*)d_in[3];
    float* out = (float*)d_out;

    float* ws_res = (float*)d_ws;           // NB floats (clamped residual term)
    float* ws_d   = ws_res + NB;            // NB floats (data-loss partials)

    darcy_wave_kernel<<<NB / 4, 256, 0, stream>>>(mo, tg, x0, var, ws_res, ws_d);
    darcy_final_kernel<<<1, 256, 0, stream>>>(ws_res, ws_d, out);
}